// Round 4
// baseline (475.508 us; speedup 1.0000x reference)
//
#include <hip/hip_runtime.h>
#include <hip/hip_bf16.h>
#include <stdint.h>

#define N_NODES 100000
#define E_EDGES 1600000
#define NEG_SLOPE 0.2f

typedef short short8 __attribute__((ext_vector_type(8)));
typedef float f32x4 __attribute__((ext_vector_type(4)));

__device__ __forceinline__ unsigned short f2bf(float f) {
  union { float f; unsigned int u; } c; c.f = f;
  unsigned int u = c.u;
  unsigned int r = u + 0x7FFFu + ((u >> 16) & 1u);
  return (unsigned short)(r >> 16);
}
__device__ __forceinline__ float asf(unsigned int u) {
  union { unsigned int u; float f; } c; c.u = u;
  return c.f;
}
__device__ __forceinline__ float bf2f(unsigned short b) { return asf(((unsigned int)b) << 16); }

// ---- detect int32 vs int64 edge_index: int64 => odd int32 words are all 0
__global__ void k_detect(const void* ei, int* flag) {
  int t = threadIdx.x;
  int v = ((const int*)ei)[2 * t + 1];
  unsigned long long b = __ballot(v != 0);
  if (t == 0) *flag = (b != 0ull) ? 1 : 0;  // 1 = int32 layout
}

// ---- pack W -> Bt[col][k] bf16, proj_w -> Pt[col][k] bf16, w3[h][d] = sum_o W_edge[h][d][o]*a3[h][o]
__global__ void k_prep(const float* __restrict__ W, const float* __restrict__ proj_w,
                       const float* __restrict__ W_edge, const float* __restrict__ att,
                       unsigned short* __restrict__ Bt, unsigned short* __restrict__ Pt,
                       float* __restrict__ w3) {
  int t = blockIdx.x * 256 + threadIdx.x;
  if (t < 65536) {
    int col = t >> 8, k = t & 255;
    int h = col >> 6, o = col & 63;
    Bt[t] = f2bf(W[h * 16384 + k * 64 + o]);
  } else if (t < 131072) {
    int t2 = t - 65536;
    int o = t2 >> 8, i = t2 & 255;
    Pt[t2] = f2bf(proj_w[i * 256 + o]);
  } else if (t < 131136) {
    int t3 = t - 131072;
    int h = t3 >> 4, d = t3 & 15;
    float s = 0.f;
    for (int o = 0; o < 64; ++o)
      s += W_edge[h * 1024 + d * 64 + o] * att[h * 192 + 128 + o];
    w3[t3] = s;
  }
}

// ---- GEMM: xwb[n][h*64+o] = bf16( sum_k x[n][k] * Bt[h*64+o][k] )
//      A-tile staged in LDS (bf16, XOR-swizzled granules: P = G ^ (row&7))
//      fused epilogue: s1[n][h], s2[n][h]  (wave w == head w)
__global__ __launch_bounds__(256, 4) void k_gemm_x(const float* __restrict__ x,
    const unsigned short* __restrict__ Bt, const float* __restrict__ att,
    unsigned short* __restrict__ xwb, float* __restrict__ s1, float* __restrict__ s2) {
  __shared__ unsigned short As[16384];  // [64 rows][256 k] bf16, swizzled, 32KB
  const int bm = blockIdx.x * 64;
  const int t = threadIdx.x;

#pragma unroll
  for (int i = 0; i < 16; ++i) {
    int c = i * 256 + t;
    int row = c >> 6, f4 = c & 63;
    uint2 w = make_uint2(0u, 0u);
    if (bm + row < N_NODES) {
      float4 v = *(const float4*)(x + (size_t)(bm + row) * 256 + f4 * 4);
      w.x = (unsigned int)f2bf(v.x) | ((unsigned int)f2bf(v.y) << 16);
      w.y = (unsigned int)f2bf(v.z) | ((unsigned int)f2bf(v.w) << 16);
    }
    int phys = row * 512 + (((f4 >> 1) ^ (row & 7)) << 4) + ((f4 & 1) << 3);
    *(uint2*)((char*)As + phys) = w;
  }
  __syncthreads();

  const int wave = t >> 6;
  const int lane = t & 63;
  const int l16 = lane & 15, lg = lane >> 4;
  const int colbase = wave * 64;
  f32x4 acc[4][4];
#pragma unroll
  for (int i = 0; i < 4; i++)
#pragma unroll
    for (int j = 0; j < 4; j++) acc[i][j] = (f32x4){0.f, 0.f, 0.f, 0.f};

  for (int ks = 0; ks < 8; ++ks) {
    const int k0 = ks * 32 + lg * 8;
    short8 a[4], b[4];
#pragma unroll
    for (int mi = 0; mi < 4; mi++) {
      int row = mi * 16 + l16;
      int phys = row * 512 + (((ks * 4 + lg) ^ (row & 7)) << 4);
      a[mi] = *(const short8*)((const char*)As + phys);
    }
#pragma unroll
    for (int ni = 0; ni < 4; ni++) {
      int col = colbase + ni * 16 + l16;
      b[ni] = *(const short8*)(Bt + col * 256 + k0);
    }
#pragma unroll
    for (int mi = 0; mi < 4; mi++)
#pragma unroll
      for (int ni = 0; ni < 4; ni++)
        acc[mi][ni] = __builtin_amdgcn_mfma_f32_16x16x32_bf16(a[mi], b[ni], acc[mi][ni], 0, 0, 0);
  }

  float a1v[4], a2v[4];
#pragma unroll
  for (int ni = 0; ni < 4; ni++) {
    a1v[ni] = att[wave * 192 + ni * 16 + l16];
    a2v[ni] = att[wave * 192 + 64 + ni * 16 + l16];
  }
#pragma unroll
  for (int mi = 0; mi < 4; mi++) {
#pragma unroll
    for (int r = 0; r < 4; r++) {
      int row = bm + mi * 16 + lg * 4 + r;
      float p1 = 0.f, p2 = 0.f;
#pragma unroll
      for (int ni = 0; ni < 4; ni++) {
        float v = acc[mi][ni][r];
        p1 += v * a1v[ni];
        p2 += v * a2v[ni];
      }
#pragma unroll
      for (int m = 1; m < 16; m <<= 1) {
        p1 += __shfl_xor(p1, m, 64);
        p2 += __shfl_xor(p2, m, 64);
      }
      if (row < N_NODES) {
#pragma unroll
        for (int ni = 0; ni < 4; ni++) {
          int col = colbase + ni * 16 + l16;
          xwb[(size_t)row * 256 + col] = f2bf(acc[mi][ni][r]);
        }
        if (l16 == 0) {
          s1[row * 4 + wave] = p1;
          s2[row * 4 + wave] = p2;
        }
      }
    }
  }
}

__global__ void k_deg(const void* ei, const int* __restrict__ flag, int* __restrict__ deg) {
  int e = blockIdx.x * 256 + threadIdx.x;
  if (e >= E_EDGES) return;
  int f = *flag;
  int dst = f ? ((const int*)ei)[E_EDGES + e] : (int)(((const long long*)ei)[E_EDGES + e]);
  atomicAdd(&deg[dst], 1);
}

__global__ void k_scan1(const int* __restrict__ deg, int* __restrict__ rowptr, int* __restrict__ bsum) {
  __shared__ int s[256];
  int t = threadIdx.x;
  int i = blockIdx.x * 256 + t;
  int orig = (i < N_NODES) ? deg[i] : 0;
  int v = orig;
  s[t] = v;
  __syncthreads();
  for (int off = 1; off < 256; off <<= 1) {
    int x = (t >= off) ? s[t - off] : 0;
    __syncthreads();
    v += x;
    s[t] = v;
    __syncthreads();
  }
  if (i < N_NODES) rowptr[i] = v - orig;  // block-local exclusive
  if (t == 255) bsum[blockIdx.x] = v;     // block total
}

__global__ void k_scan2(int* __restrict__ bsum, int nb) {
  __shared__ int s[512];
  int t = threadIdx.x;
  int v = (t < nb) ? bsum[t] : 0;
  int incl = v;
  s[t] = v;
  __syncthreads();
  for (int off = 1; off < 512; off <<= 1) {
    int x = (t >= off) ? s[t - off] : 0;
    __syncthreads();
    incl += x;
    s[t] = incl;
    __syncthreads();
  }
  if (t < nb) bsum[t] = incl - v;  // exclusive
}

__global__ void k_scan3(int* __restrict__ rowptr, const int* __restrict__ bsum, int* __restrict__ cursor) {
  int i = blockIdx.x * 256 + threadIdx.x;
  if (i < N_NODES) {
    int v = rowptr[i] + bsum[i >> 8];
    rowptr[i] = v;
    cursor[i] = v;
  }
  if (i == 0) rowptr[N_NODES] = E_EDGES;
}

// ---- per-edge: e-vals (4 heads), leakyrelu, exp; write payload ev[e] in EDGE order
//      (coalesced 16B), scatter only perm[p]=e (4B)
__global__ void k_edge(const void* ei, const int* __restrict__ flag,
                       const float* __restrict__ edge_attr,
                       const float* __restrict__ s1, const float* __restrict__ s2,
                       const float* __restrict__ w3g, int* __restrict__ cursor,
                       uint4* __restrict__ ev, int* __restrict__ perm) {
  __shared__ float w3[64];
  if (threadIdx.x < 64) w3[threadIdx.x] = w3g[threadIdx.x];
  __syncthreads();
  int e = blockIdx.x * 256 + threadIdx.x;
  if (e >= E_EDGES) return;
  int f = *flag;
  int src, dst;
  if (f) {
    src = ((const int*)ei)[e];
    dst = ((const int*)ei)[E_EDGES + e];
  } else {
    src = (int)(((const long long*)ei)[e]);
    dst = (int)(((const long long*)ei)[E_EDGES + e]);
  }
  float4 sd = *(const float4*)(s1 + (size_t)dst * 4);
  float4 ss = *(const float4*)(s2 + (size_t)src * 4);
  float ea[16];
#pragma unroll
  for (int i = 0; i < 4; i++) {
    float4 v = *(const float4*)(edge_attr + (size_t)e * 16 + i * 4);
    ea[4 * i] = v.x; ea[4 * i + 1] = v.y; ea[4 * i + 2] = v.z; ea[4 * i + 3] = v.w;
  }
  float ex[4];
#pragma unroll
  for (int h = 0; h < 4; h++) {
    float d = 0.f;
#pragma unroll
    for (int i = 0; i < 16; i++) d += ea[i] * w3[h * 16 + i];
    float v = (&sd.x)[h] + (&ss.x)[h] + d;
    v = (v >= 0.f) ? v : NEG_SLOPE * v;
    ex[h] = __expf(v);
  }
  unsigned int p0 = ((unsigned int)f2bf(ex[1]) << 16) | (unsigned int)f2bf(ex[0]);
  unsigned int p1 = ((unsigned int)f2bf(ex[3]) << 16) | (unsigned int)f2bf(ex[2]);
  ev[e] = make_uint4((unsigned int)src, p0, p1, 0u);
  int p = atomicAdd(&cursor[dst], 1);
  perm[p] = e;
}

// ---- CSR build: sequential read of perm, random 16B gather from L3-resident ev,
//      coalesced writes of src_csr/expb. Pure TLP, no dependency chains.
__global__ void k_gather(const int* __restrict__ perm, const uint4* __restrict__ ev,
                         int* __restrict__ src_csr, uint2* __restrict__ expb) {
  int i = blockIdx.x * 256 + threadIdx.x;
  if (i >= E_EDGES) return;
  uint4 v = ev[perm[i]];
  src_csr[i] = (int)v.x;
  expb[i] = make_uint2(v.y, v.z);
}

// ---- one wave per node: out_h[n][c] = (1/den) * sum_edges exp * xw[src][c]; write bf16
__global__ __launch_bounds__(256) void k_aggr(const int* __restrict__ rowptr,
    const int* __restrict__ src_csr, const uint2* __restrict__ expb,
    const unsigned short* __restrict__ xwb, unsigned short* __restrict__ out_hb) {
  int n = blockIdx.x * 4 + (threadIdx.x >> 6);
  if (n >= N_NODES) return;
  int lane = threadIdx.x & 63;
  int beg = rowptr[n], end = rowptr[n + 1];
  const int cA = 2 * lane;  // dims cA, cA+1 (A-half: heads 0/1), +128: B-half (heads 2/3)
  const bool lo32 = (lane < 32);
  float accA0 = 0.f, accA1 = 0.f, accB0 = 0.f, accB1 = 0.f;
  float den0 = 0.f, den1 = 0.f, den2 = 0.f, den3 = 0.f;

#define EDGE_FMA(eu, uA, uB)                                              \
  {                                                                       \
    float d0 = asf(eu.x << 16), d1 = asf(eu.x & 0xFFFF0000u);             \
    float d2 = asf(eu.y << 16), d3 = asf(eu.y & 0xFFFF0000u);             \
    den0 += d0; den1 += d1; den2 += d2; den3 += d3;                       \
    float wAB = lo32 ? d0 : d1;                                           \
    float wCD = lo32 ? d2 : d3;                                           \
    accA0 += wAB * asf(uA << 16); accA1 += wAB * asf(uA & 0xFFFF0000u);   \
    accB0 += wCD * asf(uB << 16); accB1 += wCD * asf(uB & 0xFFFF0000u);   \
  }

  int i = beg;
  for (; i + 4 <= end; i += 4) {
    int s0 = __builtin_amdgcn_readfirstlane(src_csr[i]);
    int s1_ = __builtin_amdgcn_readfirstlane(src_csr[i + 1]);
    int s2_ = __builtin_amdgcn_readfirstlane(src_csr[i + 2]);
    int s3_ = __builtin_amdgcn_readfirstlane(src_csr[i + 3]);
    uint2 e0 = expb[i], e1 = expb[i + 1], e2 = expb[i + 2], e3 = expb[i + 3];
    const unsigned short* r0 = xwb + (size_t)s0 * 256;
    const unsigned short* r1 = xwb + (size_t)s1_ * 256;
    const unsigned short* r2 = xwb + (size_t)s2_ * 256;
    const unsigned short* r3 = xwb + (size_t)s3_ * 256;
    unsigned int uA0 = *(const unsigned int*)(r0 + cA);
    unsigned int uB0 = *(const unsigned int*)(r0 + cA + 128);
    unsigned int uA1 = *(const unsigned int*)(r1 + cA);
    unsigned int uB1 = *(const unsigned int*)(r1 + cA + 128);
    unsigned int uA2 = *(const unsigned int*)(r2 + cA);
    unsigned int uB2 = *(const unsigned int*)(r2 + cA + 128);
    unsigned int uA3 = *(const unsigned int*)(r3 + cA);
    unsigned int uB3 = *(const unsigned int*)(r3 + cA + 128);
    EDGE_FMA(e0, uA0, uB0);
    EDGE_FMA(e1, uA1, uB1);
    EDGE_FMA(e2, uA2, uB2);
    EDGE_FMA(e3, uA3, uB3);
  }
  for (; i < end; ++i) {
    int s0 = __builtin_amdgcn_readfirstlane(src_csr[i]);
    uint2 e0 = expb[i];
    const unsigned short* r0 = xwb + (size_t)s0 * 256;
    unsigned int uA0 = *(const unsigned int*)(r0 + cA);
    unsigned int uB0 = *(const unsigned int*)(r0 + cA + 128);
    EDGE_FMA(e0, uA0, uB0);
  }
#undef EDGE_FMA

  float dA = (lo32 ? den0 : den1) + 1e-16f;
  float dB = (lo32 ? den2 : den3) + 1e-16f;
  unsigned int oA = ((unsigned int)f2bf(accA1 / dA) << 16) | (unsigned int)f2bf(accA0 / dA);
  unsigned int oB = ((unsigned int)f2bf(accB1 / dB) << 16) | (unsigned int)f2bf(accB0 / dB);
  *(unsigned int*)(out_hb + (size_t)n * 256 + cA) = oA;
  *(unsigned int*)(out_hb + (size_t)n * 256 + cA + 128) = oB;
}

// ---- out = elu(out_hb @ Pt^T + bias), A-tile staged in LDS (same swizzle)
__global__ __launch_bounds__(256, 4) void k_gemm_out(const unsigned short* __restrict__ A,
    const unsigned short* __restrict__ Pt, const float* __restrict__ bias,
    float* __restrict__ out) {
  __shared__ unsigned short As[16384];  // [64][256] bf16 swizzled
  const int bm = blockIdx.x * 64;
  const int t = threadIdx.x;

#pragma unroll
  for (int i = 0; i < 8; ++i) {
    int c = i * 256 + t;
    int row = c >> 5, G = c & 31;
    short8 v = (short8){0, 0, 0, 0, 0, 0, 0, 0};
    if (bm + row < N_NODES) v = *(const short8*)(A + (size_t)(bm + row) * 256 + G * 8);
    int phys = row * 512 + ((G ^ (row & 7)) << 4);
    *(short8*)((char*)As + phys) = v;
  }
  __syncthreads();

  const int wave = t >> 6;
  const int lane = t & 63;
  const int l16 = lane & 15, lg = lane >> 4;
  const int colbase = wave * 64;
  f32x4 acc[4][4];
#pragma unroll
  for (int i = 0; i < 4; i++)
#pragma unroll
    for (int j = 0; j < 4; j++) acc[i][j] = (f32x4){0.f, 0.f, 0.f, 0.f};

  for (int ks = 0; ks < 8; ++ks) {
    const int k0 = ks * 32 + lg * 8;
    short8 a[4], b[4];
#pragma unroll
    for (int mi = 0; mi < 4; mi++) {
      int row = mi * 16 + l16;
      int phys = row * 512 + (((ks * 4 + lg) ^ (row & 7)) << 4);
      a[mi] = *(const short8*)((const char*)As + phys);
    }
#pragma unroll
    for (int ni = 0; ni < 4; ni++) {
      int col = colbase + ni * 16 + l16;
      b[ni] = *(const short8*)(Pt + col * 256 + k0);
    }
#pragma unroll
    for (int mi = 0; mi < 4; mi++)
#pragma unroll
      for (int ni = 0; ni < 4; ni++)
        acc[mi][ni] = __builtin_amdgcn_mfma_f32_16x16x32_bf16(a[mi], b[ni], acc[mi][ni], 0, 0, 0);
  }
#pragma unroll
  for (int mi = 0; mi < 4; mi++) {
#pragma unroll
    for (int r = 0; r < 4; r++) {
      int row = bm + mi * 16 + lg * 4 + r;
      if (row < N_NODES) {
#pragma unroll
        for (int ni = 0; ni < 4; ni++) {
          int col = colbase + ni * 16 + l16;
          float v = acc[mi][ni][r] + bias[col];
          v = (v > 0.f) ? v : expm1f(v);
          out[(size_t)row * 256 + col] = v;
        }
      }
    }
  }
}

extern "C" void kernel_launch(void* const* d_in, const int* in_sizes, int n_in,
                              void* d_out, int out_size, void* d_ws, size_t ws_size,
                              hipStream_t stream) {
  const float* x = (const float*)d_in[0];
  const void* ei = d_in[1];
  const float* edge_attr = (const float*)d_in[2];
  const float* W = (const float*)d_in[3];
  const float* W_edge = (const float*)d_in[4];
  const float* att = (const float*)d_in[5];
  const float* proj_w = (const float*)d_in[6];
  const float* proj_b = (const float*)d_in[7];
  float* out = (float*)d_out;

  char* ws = (char*)d_ws;
  size_t off = 0;
  auto alloc = [&](size_t bytes) -> void* {
    void* p = (void*)(ws + off);
    off += (bytes + 255) & ~(size_t)255;
    return p;
  };
  unsigned short* xwb   = (unsigned short*)alloc((size_t)N_NODES * 256 * 2);
  unsigned short* outhb = (unsigned short*)alloc((size_t)N_NODES * 256 * 2);
  float* s1      = (float*)alloc((size_t)N_NODES * 4 * 4);
  float* s2      = (float*)alloc((size_t)N_NODES * 4 * 4);
  int* deg       = (int*)alloc((size_t)N_NODES * 4);
  int* rowptr    = (int*)alloc((size_t)(N_NODES + 1) * 4);
  int* cursor    = (int*)alloc((size_t)N_NODES * 4);
  int* bsum      = (int*)alloc(512 * 4);
  int* src_csr   = (int*)alloc((size_t)E_EDGES * 4);
  uint2* expb    = (uint2*)alloc((size_t)E_EDGES * 8);
  uint4* ev      = (uint4*)alloc((size_t)E_EDGES * 16);
  int* perm      = (int*)alloc((size_t)E_EDGES * 4);
  unsigned short* Bt = (unsigned short*)alloc(65536 * 2);
  unsigned short* Pt = (unsigned short*)alloc(65536 * 2);
  float* w3      = (float*)alloc(64 * 4);
  int* flag      = (int*)alloc(256);

  const int NB_SCAN = (N_NODES + 255) / 256;  // 391

  hipMemsetAsync(deg, 0, (size_t)N_NODES * 4, stream);
  k_detect<<<1, 64, 0, stream>>>(ei, flag);
  k_prep<<<(131136 + 255) / 256, 256, 0, stream>>>(W, proj_w, W_edge, att, Bt, Pt, w3);
  k_gemm_x<<<(N_NODES + 63) / 64, 256, 0, stream>>>(x, Bt, att, xwb, s1, s2);
  k_deg<<<(E_EDGES + 255) / 256, 256, 0, stream>>>(ei, flag, deg);
  k_scan1<<<NB_SCAN, 256, 0, stream>>>(deg, rowptr, bsum);
  k_scan2<<<1, 512, 0, stream>>>(bsum, NB_SCAN);
  k_scan3<<<NB_SCAN, 256, 0, stream>>>(rowptr, bsum, cursor);
  k_edge<<<(E_EDGES + 255) / 256, 256, 0, stream>>>(ei, flag, edge_attr, s1, s2, w3,
                                                    cursor, ev, perm);
  k_gather<<<(E_EDGES + 255) / 256, 256, 0, stream>>>(perm, ev, src_csr, expb);
  k_aggr<<<(N_NODES + 3) / 4, 256, 0, stream>>>(rowptr, src_csr, expb, xwb, outhb);
  k_gemm_out<<<(N_NODES + 63) / 64, 256, 0, stream>>>(outhb, Pt, proj_b, out);
}

// Round 5
// 376.505 us; speedup vs baseline: 1.2630x; 1.2630x over previous
//
#include <hip/hip_runtime.h>
#include <hip/hip_bf16.h>
#include <stdint.h>

#define N_NODES 100000
#define E_EDGES 1600000
#define NEG_SLOPE 0.2f
#define NBUCK 782      // ceil(N/128): bucket = 128 consecutive dst nodes
#define BK_SH 7

typedef short short8 __attribute__((ext_vector_type(8)));
typedef float f32x4 __attribute__((ext_vector_type(4)));

__device__ __forceinline__ unsigned short f2bf(float f) {
  union { float f; unsigned int u; } c; c.f = f;
  unsigned int u = c.u;
  unsigned int r = u + 0x7FFFu + ((u >> 16) & 1u);
  return (unsigned short)(r >> 16);
}
__device__ __forceinline__ float asf(unsigned int u) {
  union { unsigned int u; float f; } c; c.u = u;
  return c.f;
}

// ---- detect int32 vs int64 edge_index: int64 => odd int32 words are all 0
__global__ void k_detect(const void* ei, int* flag) {
  int t = threadIdx.x;
  int v = ((const int*)ei)[2 * t + 1];
  unsigned long long b = __ballot(v != 0);
  if (t == 0) *flag = (b != 0ull) ? 1 : 0;  // 1 = int32 layout
}

// ---- pack W -> Bt[col][k] bf16, proj_w -> Pt[col][k] bf16, w3[h][d] = sum_o W_edge[h][d][o]*a3[h][o]
__global__ void k_prep(const float* __restrict__ W, const float* __restrict__ proj_w,
                       const float* __restrict__ W_edge, const float* __restrict__ att,
                       unsigned short* __restrict__ Bt, unsigned short* __restrict__ Pt,
                       float* __restrict__ w3) {
  int t = blockIdx.x * 256 + threadIdx.x;
  if (t < 65536) {
    int col = t >> 8, k = t & 255;
    int h = col >> 6, o = col & 63;
    Bt[t] = f2bf(W[h * 16384 + k * 64 + o]);
  } else if (t < 131072) {
    int t2 = t - 65536;
    int o = t2 >> 8, i = t2 & 255;
    Pt[t2] = f2bf(proj_w[i * 256 + o]);
  } else if (t < 131136) {
    int t3 = t - 131072;
    int h = t3 >> 4, d = t3 & 15;
    float s = 0.f;
    for (int o = 0; o < 64; ++o)
      s += W_edge[h * 1024 + d * 64 + o] * att[h * 192 + 128 + o];
    w3[t3] = s;
  }
}

// ---- GEMM: xwb[n][h*64+o] = bf16( sum_k x[n][k] * Bt[h*64+o][k] )
//      A-tile staged in LDS (bf16, XOR-swizzled granules); fused s1/s2 epilogue
__global__ __launch_bounds__(256, 4) void k_gemm_x(const float* __restrict__ x,
    const unsigned short* __restrict__ Bt, const float* __restrict__ att,
    unsigned short* __restrict__ xwb, float* __restrict__ s1, float* __restrict__ s2) {
  __shared__ unsigned short As[16384];
  const int bm = blockIdx.x * 64;
  const int t = threadIdx.x;

#pragma unroll
  for (int i = 0; i < 16; ++i) {
    int c = i * 256 + t;
    int row = c >> 6, f4 = c & 63;
    uint2 w = make_uint2(0u, 0u);
    if (bm + row < N_NODES) {
      float4 v = *(const float4*)(x + (size_t)(bm + row) * 256 + f4 * 4);
      w.x = (unsigned int)f2bf(v.x) | ((unsigned int)f2bf(v.y) << 16);
      w.y = (unsigned int)f2bf(v.z) | ((unsigned int)f2bf(v.w) << 16);
    }
    int phys = row * 512 + (((f4 >> 1) ^ (row & 7)) << 4) + ((f4 & 1) << 3);
    *(uint2*)((char*)As + phys) = w;
  }
  __syncthreads();

  const int wave = t >> 6;
  const int lane = t & 63;
  const int l16 = lane & 15, lg = lane >> 4;
  const int colbase = wave * 64;
  f32x4 acc[4][4];
#pragma unroll
  for (int i = 0; i < 4; i++)
#pragma unroll
    for (int j = 0; j < 4; j++) acc[i][j] = (f32x4){0.f, 0.f, 0.f, 0.f};

  for (int ks = 0; ks < 8; ++ks) {
    const int k0 = ks * 32 + lg * 8;
    short8 a[4], b[4];
#pragma unroll
    for (int mi = 0; mi < 4; mi++) {
      int row = mi * 16 + l16;
      int phys = row * 512 + (((ks * 4 + lg) ^ (row & 7)) << 4);
      a[mi] = *(const short8*)((const char*)As + phys);
    }
#pragma unroll
    for (int ni = 0; ni < 4; ni++) {
      int col = colbase + ni * 16 + l16;
      b[ni] = *(const short8*)(Bt + col * 256 + k0);
    }
#pragma unroll
    for (int mi = 0; mi < 4; mi++)
#pragma unroll
      for (int ni = 0; ni < 4; ni++)
        acc[mi][ni] = __builtin_amdgcn_mfma_f32_16x16x32_bf16(a[mi], b[ni], acc[mi][ni], 0, 0, 0);
  }

  float a1v[4], a2v[4];
#pragma unroll
  for (int ni = 0; ni < 4; ni++) {
    a1v[ni] = att[wave * 192 + ni * 16 + l16];
    a2v[ni] = att[wave * 192 + 64 + ni * 16 + l16];
  }
#pragma unroll
  for (int mi = 0; mi < 4; mi++) {
#pragma unroll
    for (int r = 0; r < 4; r++) {
      int row = bm + mi * 16 + lg * 4 + r;
      float p1 = 0.f, p2 = 0.f;
#pragma unroll
      for (int ni = 0; ni < 4; ni++) {
        float v = acc[mi][ni][r];
        p1 += v * a1v[ni];
        p2 += v * a2v[ni];
      }
#pragma unroll
      for (int m = 1; m < 16; m <<= 1) {
        p1 += __shfl_xor(p1, m, 64);
        p2 += __shfl_xor(p2, m, 64);
      }
      if (row < N_NODES) {
#pragma unroll
        for (int ni = 0; ni < 4; ni++) {
          int col = colbase + ni * 16 + l16;
          xwb[(size_t)row * 256 + col] = f2bf(acc[mi][ni][r]);
        }
        if (l16 == 0) {
          s1[row * 4 + wave] = p1;
          s2[row * 4 + wave] = p2;
        }
      }
    }
  }
}

// ---- bucket histogram (dst>>7), LDS-staged
__global__ __launch_bounds__(1024) void k_hist(const void* ei, const int* __restrict__ flag,
                                               int* __restrict__ bhist) {
  __shared__ int h[NBUCK];
  for (int i = threadIdx.x; i < NBUCK; i += 1024) h[i] = 0;
  __syncthreads();
  int f = *flag;
  int base = blockIdx.x * 4096;
#pragma unroll
  for (int k = 0; k < 4; ++k) {
    int e = base + k * 1024 + threadIdx.x;
    if (e < E_EDGES) {
      int dst = f ? ((const int*)ei)[E_EDGES + e] : (int)(((const long long*)ei)[E_EDGES + e]);
      atomicAdd(&h[dst >> BK_SH], 1);
    }
  }
  __syncthreads();
  for (int i = threadIdx.x; i < NBUCK; i += 1024) {
    int c = h[i];
    if (c) atomicAdd(&bhist[i], c);
  }
}

// ---- exclusive scan of bucket histogram -> boff (and bcur working copy)
__global__ __launch_bounds__(1024) void k_scanb(const int* __restrict__ bhist,
                                                int* __restrict__ boff, int* __restrict__ bcur) {
  __shared__ int s[1024];
  int t = threadIdx.x;
  int v = (t < NBUCK) ? bhist[t] : 0;
  int orig = v;
  s[t] = v;
  __syncthreads();
  for (int off = 1; off < 1024; off <<= 1) {
    int x = (t >= off) ? s[t - off] : 0;
    __syncthreads();
    v += x;
    s[t] = v;
    __syncthreads();
  }
  if (t < NBUCK) {
    int excl = v - orig;
    boff[t] = excl;
    bcur[t] = excl;
  }
  if (t == 0) boff[NBUCK] = E_EDGES;
}

// ---- per-edge compute + bucket-partitioned scatter.
//      Per block: LDS bucket counts -> one global atomicAdd per (block,bucket) reserving a
//      contiguous run -> LDS-cursor placement. Scattered 16B stores land in block-private
//      runs (~5 edges avg) => near-coalesced, no cross-XCD line ping-pong.
__global__ __launch_bounds__(1024) void k_edge(const void* ei, const int* __restrict__ flag,
                       const float* __restrict__ edge_attr,
                       const float* __restrict__ s1, const float* __restrict__ s2,
                       const float* __restrict__ w3g, int* __restrict__ bcur,
                       uint4* __restrict__ evs) {
  __shared__ float w3[64];
  __shared__ int cnt[NBUCK];
  __shared__ int rb[NBUCK];
  __shared__ int cur[NBUCK];
  const int t = threadIdx.x;
  for (int i = t; i < NBUCK; i += 1024) { cnt[i] = 0; cur[i] = 0; }
  if (t < 64) w3[t] = w3g[t];
  __syncthreads();

  const int f = *flag;
  const int base = blockIdx.x * 4096;
  int dstv[4], srcv[4];
  unsigned int pav[4], pbv[4];
#pragma unroll
  for (int k = 0; k < 4; ++k) {
    int e = base + k * 1024 + t;
    dstv[k] = -1;
    if (e < E_EDGES) {
      int src, dst;
      if (f) {
        src = ((const int*)ei)[e];
        dst = ((const int*)ei)[E_EDGES + e];
      } else {
        src = (int)(((const long long*)ei)[e]);
        dst = (int)(((const long long*)ei)[E_EDGES + e]);
      }
      float4 sd = *(const float4*)(s1 + (size_t)dst * 4);
      float4 ss = *(const float4*)(s2 + (size_t)src * 4);
      float ea[16];
#pragma unroll
      for (int i = 0; i < 4; i++) {
        float4 v = *(const float4*)(edge_attr + (size_t)e * 16 + i * 4);
        ea[4 * i] = v.x; ea[4 * i + 1] = v.y; ea[4 * i + 2] = v.z; ea[4 * i + 3] = v.w;
      }
      float ex[4];
#pragma unroll
      for (int h = 0; h < 4; h++) {
        float d = 0.f;
#pragma unroll
        for (int i = 0; i < 16; i++) d += ea[i] * w3[h * 16 + i];
        float v = (&sd.x)[h] + (&ss.x)[h] + d;
        v = (v >= 0.f) ? v : NEG_SLOPE * v;
        ex[h] = __expf(v);
      }
      dstv[k] = dst;
      srcv[k] = src;
      pav[k] = ((unsigned int)f2bf(ex[1]) << 16) | (unsigned int)f2bf(ex[0]);
      pbv[k] = ((unsigned int)f2bf(ex[3]) << 16) | (unsigned int)f2bf(ex[2]);
      atomicAdd(&cnt[dst >> BK_SH], 1);
    }
  }
  __syncthreads();
  for (int i = t; i < NBUCK; i += 1024) {
    int c = cnt[i];
    if (c) rb[i] = atomicAdd(&bcur[i], c);
  }
  __syncthreads();
#pragma unroll
  for (int k = 0; k < 4; ++k) {
    if (dstv[k] >= 0) {
      int bk = dstv[k] >> BK_SH;
      int pos = rb[bk] + atomicAdd(&cur[bk], 1);
      evs[pos] = make_uint4((unsigned int)srcv[k], pav[k], pbv[k],
                            (unsigned int)(dstv[k] & 127));
    }
  }
}

// ---- one block per bucket (128 nodes): exact per-node binning in LDS, then
//      8 waves x 16 nodes aggregate; all 782 blocks co-resident (512 thr, ~18KB LDS).
__global__ __launch_bounds__(512) void k_aggr(const int* __restrict__ boff,
    const uint4* __restrict__ evs, const unsigned short* __restrict__ xwb,
    unsigned short* __restrict__ out_hb) {
  __shared__ unsigned short perm[8192];
  __shared__ int cnt[128], bs[128], cur[128];
  const int b = blockIdx.x;
  const int t = threadIdx.x;
  const int e0 = boff[b];
  const int ne = boff[b + 1] - e0;
  if (t < 128) { cnt[t] = 0; cur[t] = 0; }
  __syncthreads();
  const bool binned = (ne <= 8192);
  if (binned) {
    for (int i = t; i < ne; i += 512) atomicAdd(&cnt[evs[e0 + i].w], 1);
    __syncthreads();
    if (t < 128) bs[t] = cnt[t];
    __syncthreads();
    for (int off = 1; off < 128; off <<= 1) {
      int x = 0;
      if (t < 128 && t >= off) x = bs[t - off];
      __syncthreads();
      if (t < 128) bs[t] += x;
      __syncthreads();
    }
    for (int i = t; i < ne; i += 512) {
      int ld = evs[e0 + i].w;
      int slot = bs[ld] - cnt[ld] + atomicAdd(&cur[ld], 1);
      perm[slot] = (unsigned short)i;
    }
    __syncthreads();
  }

  const int wv = t >> 6, lane = t & 63;
  const int cA = 2 * lane;
  const bool lo32 = (lane < 32);

#define EDGE_FMA(py, pz, uA, uB)                                          \
  {                                                                       \
    float d0 = asf(py << 16), d1 = asf(py & 0xFFFF0000u);                 \
    float d2 = asf(pz << 16), d3 = asf(pz & 0xFFFF0000u);                 \
    den0 += d0; den1 += d1; den2 += d2; den3 += d3;                       \
    float wAB = lo32 ? d0 : d1;                                           \
    float wCD = lo32 ? d2 : d3;                                           \
    accA0 += wAB * asf(uA << 16); accA1 += wAB * asf(uA & 0xFFFF0000u);   \
    accB0 += wCD * asf(uB << 16); accB1 += wCD * asf(uB & 0xFFFF0000u);   \
  }

  for (int r = 0; r < 16; ++r) {
    const int ln = wv * 16 + r;
    const int n = b * 128 + ln;
    if (n >= N_NODES) break;
    float accA0 = 0.f, accA1 = 0.f, accB0 = 0.f, accB1 = 0.f;
    float den0 = 0.f, den1 = 0.f, den2 = 0.f, den3 = 0.f;
    if (binned) {
      const int je = bs[ln];
      int j = je - cnt[ln];
      for (; j + 4 <= je; j += 4) {
        int i0 = __builtin_amdgcn_readfirstlane(perm[j]);
        int i1 = __builtin_amdgcn_readfirstlane(perm[j + 1]);
        int i2 = __builtin_amdgcn_readfirstlane(perm[j + 2]);
        int i3 = __builtin_amdgcn_readfirstlane(perm[j + 3]);
        uint4 v0 = evs[e0 + i0];
        uint4 v1 = evs[e0 + i1];
        uint4 v2 = evs[e0 + i2];
        uint4 v3 = evs[e0 + i3];
        const unsigned short* r0 = xwb + (size_t)v0.x * 256;
        const unsigned short* r1 = xwb + (size_t)v1.x * 256;
        const unsigned short* r2 = xwb + (size_t)v2.x * 256;
        const unsigned short* r3 = xwb + (size_t)v3.x * 256;
        unsigned int uA0 = *(const unsigned int*)(r0 + cA);
        unsigned int uB0 = *(const unsigned int*)(r0 + cA + 128);
        unsigned int uA1 = *(const unsigned int*)(r1 + cA);
        unsigned int uB1 = *(const unsigned int*)(r1 + cA + 128);
        unsigned int uA2 = *(const unsigned int*)(r2 + cA);
        unsigned int uB2 = *(const unsigned int*)(r2 + cA + 128);
        unsigned int uA3 = *(const unsigned int*)(r3 + cA);
        unsigned int uB3 = *(const unsigned int*)(r3 + cA + 128);
        EDGE_FMA(v0.y, v0.z, uA0, uB0);
        EDGE_FMA(v1.y, v1.z, uA1, uB1);
        EDGE_FMA(v2.y, v2.z, uA2, uB2);
        EDGE_FMA(v3.y, v3.z, uA3, uB3);
      }
      for (; j < je; ++j) {
        int i0 = __builtin_amdgcn_readfirstlane(perm[j]);
        uint4 v0 = evs[e0 + i0];
        const unsigned short* r0 = xwb + (size_t)v0.x * 256;
        unsigned int uA0 = *(const unsigned int*)(r0 + cA);
        unsigned int uB0 = *(const unsigned int*)(r0 + cA + 128);
        EDGE_FMA(v0.y, v0.z, uA0, uB0);
      }
    } else {
      // statistically unreachable fallback (bucket > 8192 edges): scan with predicate
      for (int i = 0; i < ne; ++i) {
        uint4 v0 = evs[e0 + i];
        if ((int)v0.w == ln) {
          const unsigned short* r0 = xwb + (size_t)v0.x * 256;
          unsigned int uA0 = *(const unsigned int*)(r0 + cA);
          unsigned int uB0 = *(const unsigned int*)(r0 + cA + 128);
          EDGE_FMA(v0.y, v0.z, uA0, uB0);
        }
      }
    }
    float dA = (lo32 ? den0 : den1) + 1e-16f;
    float dB = (lo32 ? den2 : den3) + 1e-16f;
    unsigned int oA = ((unsigned int)f2bf(accA1 / dA) << 16) | (unsigned int)f2bf(accA0 / dA);
    unsigned int oB = ((unsigned int)f2bf(accB1 / dB) << 16) | (unsigned int)f2bf(accB0 / dB);
    *(unsigned int*)(out_hb + (size_t)n * 256 + cA) = oA;
    *(unsigned int*)(out_hb + (size_t)n * 256 + cA + 128) = oB;
  }
#undef EDGE_FMA
}

// ---- out = elu(out_hb @ Pt^T + bias), A-tile staged in LDS (same swizzle)
__global__ __launch_bounds__(256, 4) void k_gemm_out(const unsigned short* __restrict__ A,
    const unsigned short* __restrict__ Pt, const float* __restrict__ bias,
    float* __restrict__ out) {
  __shared__ unsigned short As[16384];
  const int bm = blockIdx.x * 64;
  const int t = threadIdx.x;

#pragma unroll
  for (int i = 0; i < 8; ++i) {
    int c = i * 256 + t;
    int row = c >> 5, G = c & 31;
    short8 v = (short8){0, 0, 0, 0, 0, 0, 0, 0};
    if (bm + row < N_NODES) v = *(const short8*)(A + (size_t)(bm + row) * 256 + G * 8);
    int phys = row * 512 + ((G ^ (row & 7)) << 4);
    *(short8*)((char*)As + phys) = v;
  }
  __syncthreads();

  const int wave = t >> 6;
  const int lane = t & 63;
  const int l16 = lane & 15, lg = lane >> 4;
  const int colbase = wave * 64;
  f32x4 acc[4][4];
#pragma unroll
  for (int i = 0; i < 4; i++)
#pragma unroll
    for (int j = 0; j < 4; j++) acc[i][j] = (f32x4){0.f, 0.f, 0.f, 0.f};

  for (int ks = 0; ks < 8; ++ks) {
    const int k0 = ks * 32 + lg * 8;
    short8 a[4], b[4];
#pragma unroll
    for (int mi = 0; mi < 4; mi++) {
      int row = mi * 16 + l16;
      int phys = row * 512 + (((ks * 4 + lg) ^ (row & 7)) << 4);
      a[mi] = *(const short8*)((const char*)As + phys);
    }
#pragma unroll
    for (int ni = 0; ni < 4; ni++) {
      int col = colbase + ni * 16 + l16;
      b[ni] = *(const short8*)(Pt + col * 256 + k0);
    }
#pragma unroll
    for (int mi = 0; mi < 4; mi++)
#pragma unroll
      for (int ni = 0; ni < 4; ni++)
        acc[mi][ni] = __builtin_amdgcn_mfma_f32_16x16x32_bf16(a[mi], b[ni], acc[mi][ni], 0, 0, 0);
  }
#pragma unroll
  for (int mi = 0; mi < 4; mi++) {
#pragma unroll
    for (int r = 0; r < 4; r++) {
      int row = bm + mi * 16 + lg * 4 + r;
      if (row < N_NODES) {
#pragma unroll
        for (int ni = 0; ni < 4; ni++) {
          int col = colbase + ni * 16 + l16;
          float v = acc[mi][ni][r] + bias[col];
          v = (v > 0.f) ? v : expm1f(v);
          out[(size_t)row * 256 + col] = v;
        }
      }
    }
  }
}

extern "C" void kernel_launch(void* const* d_in, const int* in_sizes, int n_in,
                              void* d_out, int out_size, void* d_ws, size_t ws_size,
                              hipStream_t stream) {
  const float* x = (const float*)d_in[0];
  const void* ei = d_in[1];
  const float* edge_attr = (const float*)d_in[2];
  const float* W = (const float*)d_in[3];
  const float* W_edge = (const float*)d_in[4];
  const float* att = (const float*)d_in[5];
  const float* proj_w = (const float*)d_in[6];
  const float* proj_b = (const float*)d_in[7];
  float* out = (float*)d_out;

  char* ws = (char*)d_ws;
  size_t off = 0;
  auto alloc = [&](size_t bytes) -> void* {
    void* p = (void*)(ws + off);
    off += (bytes + 255) & ~(size_t)255;
    return p;
  };
  unsigned short* xwb   = (unsigned short*)alloc((size_t)N_NODES * 256 * 2);
  unsigned short* outhb = (unsigned short*)alloc((size_t)N_NODES * 256 * 2);
  float* s1      = (float*)alloc((size_t)N_NODES * 4 * 4);
  float* s2      = (float*)alloc((size_t)N_NODES * 4 * 4);
  uint4* evs     = (uint4*)alloc((size_t)E_EDGES * 16);
  int* bhist     = (int*)alloc((size_t)NBUCK * 4);
  int* boff      = (int*)alloc((size_t)(NBUCK + 1) * 4);
  int* bcur      = (int*)alloc((size_t)NBUCK * 4);
  unsigned short* Bt = (unsigned short*)alloc(65536 * 2);
  unsigned short* Pt = (unsigned short*)alloc(65536 * 2);
  float* w3      = (float*)alloc(64 * 4);
  int* flag      = (int*)alloc(256);

  const int NB_E = (E_EDGES + 4095) / 4096;  // 391

  hipMemsetAsync(bhist, 0, (size_t)NBUCK * 4, stream);
  k_detect<<<1, 64, 0, stream>>>(ei, flag);
  k_prep<<<(131136 + 255) / 256, 256, 0, stream>>>(W, proj_w, W_edge, att, Bt, Pt, w3);
  k_gemm_x<<<(N_NODES + 63) / 64, 256, 0, stream>>>(x, Bt, att, xwb, s1, s2);
  k_hist<<<NB_E, 1024, 0, stream>>>(ei, flag, bhist);
  k_scanb<<<1, 1024, 0, stream>>>(bhist, boff, bcur);
  k_edge<<<NB_E, 1024, 0, stream>>>(ei, flag, edge_attr, s1, s2, w3, bcur, evs);
  k_aggr<<<NBUCK, 512, 0, stream>>>(boff, evs, xwb, outhb);
  k_gemm_out<<<(N_NODES + 63) / 64, 256, 0, stream>>>(outhb, Pt, proj_b, out);
}

// Round 6
// 373.762 us; speedup vs baseline: 1.2722x; 1.0073x over previous
//
#include <hip/hip_runtime.h>
#include <hip/hip_bf16.h>
#include <stdint.h>

#define N_NODES 100000
#define E_EDGES 1600000
#define NEG_SLOPE 0.2f
#define NBUCK 782      // ceil(N/128): bucket = 128 consecutive dst nodes
#define BK_SH 7

typedef short short8 __attribute__((ext_vector_type(8)));
typedef float f32x4 __attribute__((ext_vector_type(4)));

__device__ __forceinline__ unsigned short f2bf(float f) {
  union { float f; unsigned int u; } c; c.f = f;
  unsigned int u = c.u;
  unsigned int r = u + 0x7FFFu + ((u >> 16) & 1u);
  return (unsigned short)(r >> 16);
}
__device__ __forceinline__ float asf(unsigned int u) {
  union { unsigned int u; float f; } c; c.u = u;
  return c.f;
}

// ---- detect int32 vs int64 edge_index: int64 => odd int32 words are all 0
__global__ void k_detect(const void* ei, int* flag) {
  int t = threadIdx.x;
  int v = ((const int*)ei)[2 * t + 1];
  unsigned long long b = __ballot(v != 0);
  if (t == 0) *flag = (b != 0ull) ? 1 : 0;  // 1 = int32 layout
}

// ---- pack W -> Bt[col][k] bf16, proj_w -> Pt[col][k] bf16, w3[h][d] = sum_o W_edge[h][d][o]*a3[h][o]
__global__ void k_prep(const float* __restrict__ W, const float* __restrict__ proj_w,
                       const float* __restrict__ W_edge, const float* __restrict__ att,
                       unsigned short* __restrict__ Bt, unsigned short* __restrict__ Pt,
                       float* __restrict__ w3) {
  int t = blockIdx.x * 256 + threadIdx.x;
  if (t < 65536) {
    int col = t >> 8, k = t & 255;
    int h = col >> 6, o = col & 63;
    Bt[t] = f2bf(W[h * 16384 + k * 64 + o]);
  } else if (t < 131072) {
    int t2 = t - 65536;
    int o = t2 >> 8, i = t2 & 255;
    Pt[t2] = f2bf(proj_w[i * 256 + o]);
  } else if (t < 131136) {
    int t3 = t - 131072;
    int h = t3 >> 4, d = t3 & 15;
    float s = 0.f;
    for (int o = 0; o < 64; ++o)
      s += W_edge[h * 1024 + d * 64 + o] * att[h * 192 + 128 + o];
    w3[t3] = s;
  }
}

// ---- GEMM: xwb[n][h*64+o] = bf16( sum_k x[n][k] * Bt[h*64+o][k] )
//      A-tile staged in LDS (bf16, XOR-swizzled granules); fused s1/s2 epilogue
__global__ __launch_bounds__(256, 4) void k_gemm_x(const float* __restrict__ x,
    const unsigned short* __restrict__ Bt, const float* __restrict__ att,
    unsigned short* __restrict__ xwb, float* __restrict__ s1, float* __restrict__ s2) {
  __shared__ unsigned short As[16384];
  const int bm = blockIdx.x * 64;
  const int t = threadIdx.x;

#pragma unroll
  for (int i = 0; i < 16; ++i) {
    int c = i * 256 + t;
    int row = c >> 6, f4 = c & 63;
    uint2 w = make_uint2(0u, 0u);
    if (bm + row < N_NODES) {
      float4 v = *(const float4*)(x + (size_t)(bm + row) * 256 + f4 * 4);
      w.x = (unsigned int)f2bf(v.x) | ((unsigned int)f2bf(v.y) << 16);
      w.y = (unsigned int)f2bf(v.z) | ((unsigned int)f2bf(v.w) << 16);
    }
    int phys = row * 512 + (((f4 >> 1) ^ (row & 7)) << 4) + ((f4 & 1) << 3);
    *(uint2*)((char*)As + phys) = w;
  }
  __syncthreads();

  const int wave = t >> 6;
  const int lane = t & 63;
  const int l16 = lane & 15, lg = lane >> 4;
  const int colbase = wave * 64;
  f32x4 acc[4][4];
#pragma unroll
  for (int i = 0; i < 4; i++)
#pragma unroll
    for (int j = 0; j < 4; j++) acc[i][j] = (f32x4){0.f, 0.f, 0.f, 0.f};

  for (int ks = 0; ks < 8; ++ks) {
    const int k0 = ks * 32 + lg * 8;
    short8 a[4], b[4];
#pragma unroll
    for (int mi = 0; mi < 4; mi++) {
      int row = mi * 16 + l16;
      int phys = row * 512 + (((ks * 4 + lg) ^ (row & 7)) << 4);
      a[mi] = *(const short8*)((const char*)As + phys);
    }
#pragma unroll
    for (int ni = 0; ni < 4; ni++) {
      int col = colbase + ni * 16 + l16;
      b[ni] = *(const short8*)(Bt + col * 256 + k0);
    }
#pragma unroll
    for (int mi = 0; mi < 4; mi++)
#pragma unroll
      for (int ni = 0; ni < 4; ni++)
        acc[mi][ni] = __builtin_amdgcn_mfma_f32_16x16x32_bf16(a[mi], b[ni], acc[mi][ni], 0, 0, 0);
  }

  float a1v[4], a2v[4];
#pragma unroll
  for (int ni = 0; ni < 4; ni++) {
    a1v[ni] = att[wave * 192 + ni * 16 + l16];
    a2v[ni] = att[wave * 192 + 64 + ni * 16 + l16];
  }
#pragma unroll
  for (int mi = 0; mi < 4; mi++) {
#pragma unroll
    for (int r = 0; r < 4; r++) {
      int row = bm + mi * 16 + lg * 4 + r;
      float p1 = 0.f, p2 = 0.f;
#pragma unroll
      for (int ni = 0; ni < 4; ni++) {
        float v = acc[mi][ni][r];
        p1 += v * a1v[ni];
        p2 += v * a2v[ni];
      }
#pragma unroll
      for (int m = 1; m < 16; m <<= 1) {
        p1 += __shfl_xor(p1, m, 64);
        p2 += __shfl_xor(p2, m, 64);
      }
      if (row < N_NODES) {
#pragma unroll
        for (int ni = 0; ni < 4; ni++) {
          int col = colbase + ni * 16 + l16;
          xwb[(size_t)row * 256 + col] = f2bf(acc[mi][ni][r]);
        }
        if (l16 == 0) {
          s1[row * 4 + wave] = p1;
          s2[row * 4 + wave] = p2;
        }
      }
    }
  }
}

// ---- bucket histogram (dst>>7), LDS-staged
__global__ __launch_bounds__(1024) void k_hist(const void* ei, const int* __restrict__ flag,
                                               int* __restrict__ bhist) {
  __shared__ int h[NBUCK];
  for (int i = threadIdx.x; i < NBUCK; i += 1024) h[i] = 0;
  __syncthreads();
  int f = *flag;
  int base = blockIdx.x * 4096;
#pragma unroll
  for (int k = 0; k < 4; ++k) {
    int e = base + k * 1024 + threadIdx.x;
    if (e < E_EDGES) {
      int dst = f ? ((const int*)ei)[E_EDGES + e] : (int)(((const long long*)ei)[E_EDGES + e]);
      atomicAdd(&h[dst >> BK_SH], 1);
    }
  }
  __syncthreads();
  for (int i = threadIdx.x; i < NBUCK; i += 1024) {
    int c = h[i];
    if (c) atomicAdd(&bhist[i], c);
  }
}

// ---- exclusive scan of bucket histogram -> boff (and bcur working copy)
__global__ __launch_bounds__(1024) void k_scanb(const int* __restrict__ bhist,
                                                int* __restrict__ boff, int* __restrict__ bcur) {
  __shared__ int s[1024];
  int t = threadIdx.x;
  int v = (t < NBUCK) ? bhist[t] : 0;
  int orig = v;
  s[t] = v;
  __syncthreads();
  for (int off = 1; off < 1024; off <<= 1) {
    int x = (t >= off) ? s[t - off] : 0;
    __syncthreads();
    v += x;
    s[t] = v;
    __syncthreads();
  }
  if (t < NBUCK) {
    int excl = v - orig;
    boff[t] = excl;
    bcur[t] = excl;
  }
  if (t == 0) boff[NBUCK] = E_EDGES;
}

// ---- per-edge compute + bucket-partitioned scatter (block-private runs)
__global__ __launch_bounds__(1024) void k_edge(const void* ei, const int* __restrict__ flag,
                       const float* __restrict__ edge_attr,
                       const float* __restrict__ s1, const float* __restrict__ s2,
                       const float* __restrict__ w3g, int* __restrict__ bcur,
                       uint4* __restrict__ evs) {
  __shared__ float w3[64];
  __shared__ int cnt[NBUCK];
  __shared__ int rb[NBUCK];
  __shared__ int cur[NBUCK];
  const int t = threadIdx.x;
  for (int i = t; i < NBUCK; i += 1024) { cnt[i] = 0; cur[i] = 0; }
  if (t < 64) w3[t] = w3g[t];
  __syncthreads();

  const int f = *flag;
  const int base = blockIdx.x * 4096;
  int dstv[4], srcv[4];
  unsigned int pav[4], pbv[4];
#pragma unroll
  for (int k = 0; k < 4; ++k) {
    int e = base + k * 1024 + t;
    dstv[k] = -1;
    if (e < E_EDGES) {
      int src, dst;
      if (f) {
        src = ((const int*)ei)[e];
        dst = ((const int*)ei)[E_EDGES + e];
      } else {
        src = (int)(((const long long*)ei)[e]);
        dst = (int)(((const long long*)ei)[E_EDGES + e]);
      }
      float4 sd = *(const float4*)(s1 + (size_t)dst * 4);
      float4 ss = *(const float4*)(s2 + (size_t)src * 4);
      float ea[16];
#pragma unroll
      for (int i = 0; i < 4; i++) {
        float4 v = *(const float4*)(edge_attr + (size_t)e * 16 + i * 4);
        ea[4 * i] = v.x; ea[4 * i + 1] = v.y; ea[4 * i + 2] = v.z; ea[4 * i + 3] = v.w;
      }
      float ex[4];
#pragma unroll
      for (int h = 0; h < 4; h++) {
        float d = 0.f;
#pragma unroll
        for (int i = 0; i < 16; i++) d += ea[i] * w3[h * 16 + i];
        float v = (&sd.x)[h] + (&ss.x)[h] + d;
        v = (v >= 0.f) ? v : NEG_SLOPE * v;
        ex[h] = __expf(v);
      }
      dstv[k] = dst;
      srcv[k] = src;
      pav[k] = ((unsigned int)f2bf(ex[1]) << 16) | (unsigned int)f2bf(ex[0]);
      pbv[k] = ((unsigned int)f2bf(ex[3]) << 16) | (unsigned int)f2bf(ex[2]);
      atomicAdd(&cnt[dst >> BK_SH], 1);
    }
  }
  __syncthreads();
  for (int i = t; i < NBUCK; i += 1024) {
    int c = cnt[i];
    if (c) rb[i] = atomicAdd(&bcur[i], c);
  }
  __syncthreads();
#pragma unroll
  for (int k = 0; k < 4; ++k) {
    if (dstv[k] >= 0) {
      int bk = dstv[k] >> BK_SH;
      int pos = rb[bk] + atomicAdd(&cur[bk], 1);
      evs[pos] = make_uint4((unsigned int)srcv[k], pav[k], pbv[k],
                            (unsigned int)(dstv[k] & 127));
    }
  }
}

// ---- one block per bucket (128 nodes): exact per-node binning in LDS, then
//      8 waves x 16 nodes. Lane l owns shorts [4l,4l+4) of the row (head = l>>4):
//      ONE 8B gather per lane per edge, no cross-lane reduce, coalesced 8B out.
__global__ __launch_bounds__(512) void k_aggr(const int* __restrict__ boff,
    const uint4* __restrict__ evs, const unsigned short* __restrict__ xwb,
    unsigned short* __restrict__ out_hb) {
  __shared__ unsigned short perm[8192];
  __shared__ int cnt[128], bs[128], cur[128];
  const int b = blockIdx.x;
  const int t = threadIdx.x;
  const int e0 = boff[b];
  const int ne = boff[b + 1] - e0;
  if (t < 128) { cnt[t] = 0; cur[t] = 0; }
  __syncthreads();
  const bool binned = (ne <= 8192);
  if (binned) {
    for (int i = t; i < ne; i += 512) atomicAdd(&cnt[evs[e0 + i].w], 1);
    __syncthreads();
    if (t < 128) bs[t] = cnt[t];
    __syncthreads();
    for (int off = 1; off < 128; off <<= 1) {
      int x = 0;
      if (t < 128 && t >= off) x = bs[t - off];
      __syncthreads();
      if (t < 128) bs[t] += x;
      __syncthreads();
    }
    for (int i = t; i < ne; i += 512) {
      int ld = evs[e0 + i].w;
      int slot = bs[ld] - cnt[ld] + atomicAdd(&cur[ld], 1);
      perm[slot] = (unsigned short)i;
    }
    __syncthreads();
  }

  const int wv = t >> 6, lane = t & 63;
  const int sh = lane * 4;            // short offset within row: lane covers [4l, 4l+4)
  const int hsel = lane >> 4;         // head owned by this lane
  const bool hlo2 = (hsel < 2);
  const bool hodd = (hsel & 1);

#define EDGE_FMA(v, u)                                                    \
  {                                                                       \
    unsigned int wp = hlo2 ? (v).y : (v).z;                               \
    float wlo = asf(wp << 16), whi = asf(wp & 0xFFFF0000u);               \
    float w = hodd ? whi : wlo;                                           \
    den += w;                                                             \
    acc0 += w * asf((u).x << 16); acc1 += w * asf((u).x & 0xFFFF0000u);   \
    acc2 += w * asf((u).y << 16); acc3 += w * asf((u).y & 0xFFFF0000u);   \
  }

  for (int r = 0; r < 16; ++r) {
    const int ln = wv * 16 + r;
    const int n = b * 128 + ln;
    if (n >= N_NODES) break;
    float acc0 = 0.f, acc1 = 0.f, acc2 = 0.f, acc3 = 0.f, den = 0.f;
    if (binned) {
      const int je = bs[ln];
      int j = je - cnt[ln];
      for (; j + 4 <= je; j += 4) {
        int i0 = __builtin_amdgcn_readfirstlane(perm[j]);
        int i1 = __builtin_amdgcn_readfirstlane(perm[j + 1]);
        int i2 = __builtin_amdgcn_readfirstlane(perm[j + 2]);
        int i3 = __builtin_amdgcn_readfirstlane(perm[j + 3]);
        uint4 v0 = evs[e0 + i0];
        uint4 v1 = evs[e0 + i1];
        uint4 v2 = evs[e0 + i2];
        uint4 v3 = evs[e0 + i3];
        uint2 u0 = *(const uint2*)(xwb + (size_t)v0.x * 256 + sh);
        uint2 u1 = *(const uint2*)(xwb + (size_t)v1.x * 256 + sh);
        uint2 u2 = *(const uint2*)(xwb + (size_t)v2.x * 256 + sh);
        uint2 u3 = *(const uint2*)(xwb + (size_t)v3.x * 256 + sh);
        EDGE_FMA(v0, u0);
        EDGE_FMA(v1, u1);
        EDGE_FMA(v2, u2);
        EDGE_FMA(v3, u3);
      }
      for (; j < je; ++j) {
        int i0 = __builtin_amdgcn_readfirstlane(perm[j]);
        uint4 v0 = evs[e0 + i0];
        uint2 u0 = *(const uint2*)(xwb + (size_t)v0.x * 256 + sh);
        EDGE_FMA(v0, u0);
      }
    } else {
      // statistically unreachable fallback (bucket > 8192 edges)
      for (int i = 0; i < ne; ++i) {
        uint4 v0 = evs[e0 + i];
        if ((int)v0.w == ln) {
          uint2 u0 = *(const uint2*)(xwb + (size_t)v0.x * 256 + sh);
          EDGE_FMA(v0, u0);
        }
      }
    }
    float d = den + 1e-16f;
    uint2 o;
    o.x = ((unsigned int)f2bf(acc1 / d) << 16) | (unsigned int)f2bf(acc0 / d);
    o.y = ((unsigned int)f2bf(acc3 / d) << 16) | (unsigned int)f2bf(acc2 / d);
    *(uint2*)(out_hb + (size_t)n * 256 + sh) = o;
  }
#undef EDGE_FMA
}

// ---- out = elu(out_hb @ Pt^T + bias), A-tile staged in LDS (same swizzle)
__global__ __launch_bounds__(256, 4) void k_gemm_out(const unsigned short* __restrict__ A,
    const unsigned short* __restrict__ Pt, const float* __restrict__ bias,
    float* __restrict__ out) {
  __shared__ unsigned short As[16384];
  const int bm = blockIdx.x * 64;
  const int t = threadIdx.x;

#pragma unroll
  for (int i = 0; i < 8; ++i) {
    int c = i * 256 + t;
    int row = c >> 5, G = c & 31;
    short8 v = (short8){0, 0, 0, 0, 0, 0, 0, 0};
    if (bm + row < N_NODES) v = *(const short8*)(A + (size_t)(bm + row) * 256 + G * 8);
    int phys = row * 512 + ((G ^ (row & 7)) << 4);
    *(short8*)((char*)As + phys) = v;
  }
  __syncthreads();

  const int wave = t >> 6;
  const int lane = t & 63;
  const int l16 = lane & 15, lg = lane >> 4;
  const int colbase = wave * 64;
  f32x4 acc[4][4];
#pragma unroll
  for (int i = 0; i < 4; i++)
#pragma unroll
    for (int j = 0; j < 4; j++) acc[i][j] = (f32x4){0.f, 0.f, 0.f, 0.f};

  for (int ks = 0; ks < 8; ++ks) {
    const int k0 = ks * 32 + lg * 8;
    short8 a[4], b[4];
#pragma unroll
    for (int mi = 0; mi < 4; mi++) {
      int row = mi * 16 + l16;
      int phys = row * 512 + (((ks * 4 + lg) ^ (row & 7)) << 4);
      a[mi] = *(const short8*)((const char*)As + phys);
    }
#pragma unroll
    for (int ni = 0; ni < 4; ni++) {
      int col = colbase + ni * 16 + l16;
      b[ni] = *(const short8*)(Pt + col * 256 + k0);
    }
#pragma unroll
    for (int mi = 0; mi < 4; mi++)
#pragma unroll
      for (int ni = 0; ni < 4; ni++)
        acc[mi][ni] = __builtin_amdgcn_mfma_f32_16x16x32_bf16(a[mi], b[ni], acc[mi][ni], 0, 0, 0);
  }
#pragma unroll
  for (int mi = 0; mi < 4; mi++) {
#pragma unroll
    for (int r = 0; r < 4; r++) {
      int row = bm + mi * 16 + lg * 4 + r;
      if (row < N_NODES) {
#pragma unroll
        for (int ni = 0; ni < 4; ni++) {
          int col = colbase + ni * 16 + l16;
          float v = acc[mi][ni][r] + bias[col];
          v = (v > 0.f) ? v : expm1f(v);
          out[(size_t)row * 256 + col] = v;
        }
      }
    }
  }
}

extern "C" void kernel_launch(void* const* d_in, const int* in_sizes, int n_in,
                              void* d_out, int out_size, void* d_ws, size_t ws_size,
                              hipStream_t stream) {
  const float* x = (const float*)d_in[0];
  const void* ei = d_in[1];
  const float* edge_attr = (const float*)d_in[2];
  const float* W = (const float*)d_in[3];
  const float* W_edge = (const float*)d_in[4];
  const float* att = (const float*)d_in[5];
  const float* proj_w = (const float*)d_in[6];
  const float* proj_b = (const float*)d_in[7];
  float* out = (float*)d_out;

  char* ws = (char*)d_ws;
  size_t off = 0;
  auto alloc = [&](size_t bytes) -> void* {
    void* p = (void*)(ws + off);
    off += (bytes + 255) & ~(size_t)255;
    return p;
  };
  unsigned short* xwb   = (unsigned short*)alloc((size_t)N_NODES * 256 * 2);
  unsigned short* outhb = (unsigned short*)alloc((size_t)N_NODES * 256 * 2);
  float* s1      = (float*)alloc((size_t)N_NODES * 4 * 4);
  float* s2      = (float*)alloc((size_t)N_NODES * 4 * 4);
  uint4* evs     = (uint4*)alloc((size_t)E_EDGES * 16);
  int* bhist     = (int*)alloc((size_t)NBUCK * 4);
  int* boff      = (int*)alloc((size_t)(NBUCK + 1) * 4);
  int* bcur      = (int*)alloc((size_t)NBUCK * 4);
  unsigned short* Bt = (unsigned short*)alloc(65536 * 2);
  unsigned short* Pt = (unsigned short*)alloc(65536 * 2);
  float* w3      = (float*)alloc(64 * 4);
  int* flag      = (int*)alloc(256);

  const int NB_E = (E_EDGES + 4095) / 4096;  // 391

  hipMemsetAsync(bhist, 0, (size_t)NBUCK * 4, stream);
  k_detect<<<1, 64, 0, stream>>>(ei, flag);
  k_prep<<<(131136 + 255) / 256, 256, 0, stream>>>(W, proj_w, W_edge, att, Bt, Pt, w3);
  k_gemm_x<<<(N_NODES + 63) / 64, 256, 0, stream>>>(x, Bt, att, xwb, s1, s2);
  k_hist<<<NB_E, 1024, 0, stream>>>(ei, flag, bhist);
  k_scanb<<<1, 1024, 0, stream>>>(bhist, boff, bcur);
  k_edge<<<NB_E, 1024, 0, stream>>>(ei, flag, edge_attr, s1, s2, w3, bcur, evs);
  k_aggr<<<NBUCK, 512, 0, stream>>>(boff, evs, xwb, outhb);
  k_gemm_out<<<(N_NODES + 63) / 64, 256, 0, stream>>>(outhb, Pt, proj_b, out);
}